// Round 1
// baseline (376.530 us; speedup 1.0000x reference)
//
#include <hip/hip_runtime.h>
#include <stdint.h>

#define S_LEN 2048
#define NHEAD 16
#define HDIM  64
#define HIDDEN 1024
#define BATCH 4

typedef float f32x4 __attribute__((ext_vector_type(4)));
typedef __bf16 bf16x8 __attribute__((ext_vector_type(8)));
typedef unsigned short u16;

union U4B8 { uint4 u; bf16x8 b; };

__device__ __forceinline__ bf16x8 as_b8(uint4 u){ U4B8 x; x.u = u; return x.b; }

__device__ __forceinline__ f32x4 mfma16(uint4 a, uint4 b, f32x4 c){
  return __builtin_amdgcn_mfma_f32_16x16x32_bf16(as_b8(a), as_b8(b), c, 0, 0, 0);
}

__device__ __forceinline__ u16 f2bf(float f){
  unsigned u = __float_as_uint(f);
  u += 0x7FFFu + ((u >> 16) & 1u);
  return (u16)(u >> 16);
}

__device__ __forceinline__ void gload16(const void* g, void* l){
  __builtin_amdgcn_global_load_lds(
      (const __attribute__((address_space(1))) unsigned int*)g,
      (__attribute__((address_space(3))) unsigned int*)l, 16, 0, 0);
}

// ---------------- convert x: f32 -> bf16, 4 elems/thread/iter ----------------
__global__ __launch_bounds__(256) void k_cvt(const float* __restrict__ in,
                                             u16* __restrict__ out, int n4){
  int i = blockIdx.x * 256 + threadIdx.x;
  int stride = gridDim.x * 256;
  for (; i < n4; i += stride){
    float4 v = ((const float4*)in)[i];
    unsigned lo = (unsigned)f2bf(v.x) | ((unsigned)f2bf(v.y) << 16);
    unsigned hi = (unsigned)f2bf(v.z) | ((unsigned)f2bf(v.w) << 16);
    ((uint2*)out)[i] = make_uint2(lo, hi);
  }
}

// ---------------- transpose+convert: f32 [K][N] -> bf16 [N][K] ----------------
__global__ __launch_bounds__(256) void k_transpose(const float* __restrict__ in,
                                                   u16* __restrict__ out,
                                                   int K, int N){
  __shared__ float t[32][33];
  int tx = threadIdx.x & 31, ty = threadIdx.x >> 5;
  int n0 = blockIdx.x * 32, k0 = blockIdx.y * 32;
  #pragma unroll
  for (int i = 0; i < 4; ++i)
    t[ty + i*8][tx] = in[(size_t)(k0 + ty + i*8) * N + n0 + tx];
  __syncthreads();
  #pragma unroll
  for (int i = 0; i < 4; ++i)
    out[(size_t)(n0 + ty + i*8) * K + k0 + tx] = f2bf(t[tx][ty + i*8]);
}

// ---------------- GEMM: C[M,N] = A[M,K](bf16) @ Bt[N,K](bf16)^T + bias -------
// MODE 0: scatter into q/k/v [B*H][S][D] bf16.  MODE 1: f32 out [M,N].
template<int MODE>
__global__ __launch_bounds__(256) void k_gemm(
    const u16* __restrict__ A, const u16* __restrict__ Bt,
    const float* __restrict__ bias,
    u16* __restrict__ oq, u16* __restrict__ ok, u16* __restrict__ ov,
    float* __restrict__ of, int M, int N, int K)
{
  __shared__ u16 As[128 * 32];
  __shared__ u16 Bs[128 * 32];
  const int tid  = threadIdx.x;
  const int wave = tid >> 6, lane = tid & 63;
  const int l4 = lane >> 4, lm = lane & 15;
  const int wr = wave >> 1, wc = wave & 1;
  const int row0 = blockIdx.y * 128;
  const int col0 = blockIdx.x * 128;

  const f32x4 fzero = {0.f, 0.f, 0.f, 0.f};
  f32x4 acc[4][4];
  #pragma unroll
  for (int m = 0; m < 4; ++m)
    #pragma unroll
    for (int n = 0; n < 4; ++n) acc[m][n] = fzero;

  for (int k0 = 0; k0 < K; k0 += 32){
    #pragma unroll
    for (int p = 0; p < 2; ++p){
      int chunk = wave * 128 + p * 64 + lane;
      int r = chunk >> 2, cseg = chunk & 3;
      const u16* ga = A  + (size_t)(row0 + r) * K + k0 + cseg * 8;
      gload16(ga, &As[(wave * 128 + p * 64) * 8]);
      const u16* gb = Bt + (size_t)(col0 + r) * K + k0 + cseg * 8;
      gload16(gb, &Bs[(wave * 128 + p * 64) * 8]);
    }
    __syncthreads();
    uint4 af[4], bf[4];
    #pragma unroll
    for (int m = 0; m < 4; ++m)
      af[m] = *(const uint4*)&As[(wr * 64 + m * 16 + lm) * 32 + l4 * 8];
    #pragma unroll
    for (int n = 0; n < 4; ++n)
      bf[n] = *(const uint4*)&Bs[(wc * 64 + n * 16 + lm) * 32 + l4 * 8];
    #pragma unroll
    for (int m = 0; m < 4; ++m)
      #pragma unroll
      for (int n = 0; n < 4; ++n)
        acc[m][n] = mfma16(af[m], bf[n], acc[m][n]);
    __syncthreads();
  }

  #pragma unroll
  for (int m = 0; m < 4; ++m){
    #pragma unroll
    for (int n = 0; n < 4; ++n){
      int c = col0 + wc * 64 + n * 16 + lm;
      float bv = bias[c];
      #pragma unroll
      for (int r = 0; r < 4; ++r){
        int row = row0 + wr * 64 + m * 16 + l4 * 4 + r;
        float val = acc[m][n][r] + bv;
        if (MODE == 0){
          int h = c / 192, e = c % 192;
          int which = e >> 6, d = e & 63;
          int b = row >> 11, s = row & 2047;
          size_t idx = ((size_t)(b * 16 + h) * S_LEN + s) * HDIM + d;
          u16* dst = (which == 0) ? oq : ((which == 1) ? ok : ov);
          dst[idx] = f2bf(val);
        } else {
          of[(size_t)row * N + c] = val;
        }
      }
    }
  }
}

// ---------------- causal flash attention ----------------
// grid: 2048 blocks; bh = bid>>5 (0..63), qt = bid&31.  4 waves x 16 q-rows.
__global__ __launch_bounds__(256) void k_attn(
    const u16* __restrict__ q, const u16* __restrict__ kk,
    const u16* __restrict__ vv, u16* __restrict__ ctx)
{
  __shared__ u16 Ks[64][72];
  __shared__ u16 Vt[64][72];
  __shared__ u16 Ps[4][16][72];

  const int bid = blockIdx.x;
  const int bh = bid >> 5, qt = bid & 31;
  const int tid = threadIdx.x, wave = tid >> 6, lane = tid & 63;
  const int l4 = lane >> 4, lm = lane & 15;
  const int qbase = qt * 64 + wave * 16;
  const float scale = 0.125f;
  const size_t base = (size_t)bh * S_LEN * HDIM;

  uint4 qf0, qf1;
  {
    const u16* qr = q + base + (size_t)(qbase + lm) * HDIM + l4 * 8;
    qf0 = *(const uint4*)qr;
    qf1 = *(const uint4*)(qr + 32);
  }

  const f32x4 fzero = {0.f, 0.f, 0.f, 0.f};
  float mr[4], lsum[4];
  f32x4 acc[4];
  #pragma unroll
  for (int r = 0; r < 4; ++r){ mr[r] = -1e30f; lsum[r] = 0.f; }
  #pragma unroll
  for (int t = 0; t < 4; ++t) acc[t] = fzero;

  for (int kt = 0; kt <= qt; ++kt){
    // ---- stage K rows + V transposed ----
    {
      int r = tid >> 2, c0 = (tid & 3) * 16;
      const u16* kg = kk + base + (size_t)(kt * 64 + r) * HDIM + c0;
      uint4 a = *(const uint4*)kg;
      uint4 b = *(const uint4*)(kg + 8);
      *(uint4*)&Ks[r][c0]     = a;
      *(uint4*)&Ks[r][c0 + 8] = b;
      const u16* vg = vv + base + (size_t)(kt * 64 + r) * HDIM + c0;
      uint4 c = *(const uint4*)vg;
      uint4 d = *(const uint4*)(vg + 8);
      u16 tmp[16];
      *(uint4*)&tmp[0] = c; *(uint4*)&tmp[8] = d;
      #pragma unroll
      for (int j = 0; j < 16; ++j) Vt[c0 + j][r] = tmp[j];
    }
    __syncthreads();

    // ---- S = Q K^T (scaled) ----
    float sreg[4][4];
    #pragma unroll
    for (int g = 0; g < 4; ++g){
      uint4 b0 = *(const uint4*)&Ks[g * 16 + lm][l4 * 8];
      uint4 b1 = *(const uint4*)&Ks[g * 16 + lm][32 + l4 * 8];
      f32x4 sv = fzero;
      sv = mfma16(qf0, b0, sv);
      sv = mfma16(qf1, b1, sv);
      #pragma unroll
      for (int r = 0; r < 4; ++r) sreg[g][r] = sv[r] * scale;
    }
    if (kt == qt){
      #pragma unroll
      for (int g = 0; g < 4; ++g)
        #pragma unroll
        for (int r = 0; r < 4; ++r){
          int kc  = g * 16 + lm;
          int qr_ = wave * 16 + l4 * 4 + r;
          if (kc > qr_) sreg[g][r] = -1e30f;
        }
    }

    // ---- online softmax ----
    float pm[4];
    #pragma unroll
    for (int r = 0; r < 4; ++r)
      pm[r] = fmaxf(fmaxf(sreg[0][r], sreg[1][r]), fmaxf(sreg[2][r], sreg[3][r]));
    #pragma unroll
    for (int off = 1; off < 16; off <<= 1)
      #pragma unroll
      for (int r = 0; r < 4; ++r)
        pm[r] = fmaxf(pm[r], __shfl_xor(pm[r], off));

    float p[4][4], psum[4];
    #pragma unroll
    for (int r = 0; r < 4; ++r){
      float mn = fmaxf(mr[r], pm[r]);
      float corr = __expf(mr[r] - mn);
      mr[r] = mn;
      lsum[r] *= corr;
      #pragma unroll
      for (int t = 0; t < 4; ++t) acc[t][r] *= corr;
      float ps = 0.f;
      #pragma unroll
      for (int g = 0; g < 4; ++g){ p[g][r] = __expf(sreg[g][r] - mn); ps += p[g][r]; }
      psum[r] = ps;
    }
    #pragma unroll
    for (int off = 1; off < 16; off <<= 1)
      #pragma unroll
      for (int r = 0; r < 4; ++r)
        psum[r] += __shfl_xor(psum[r], off);
    #pragma unroll
    for (int r = 0; r < 4; ++r) lsum[r] += psum[r];

    // ---- P -> bf16 -> LDS (per-wave region), re-read as A-fragments ----
    #pragma unroll
    for (int g = 0; g < 4; ++g)
      #pragma unroll
      for (int r = 0; r < 4; ++r)
        Ps[wave][l4 * 4 + r][g * 16 + lm] = f2bf(p[g][r]);
    __builtin_amdgcn_wave_barrier();
    uint4 pa0 = *(const uint4*)&Ps[wave][lm][l4 * 8];
    uint4 pa1 = *(const uint4*)&Ps[wave][lm][32 + l4 * 8];

    // ---- O += P @ V ----
    #pragma unroll
    for (int t = 0; t < 4; ++t){
      uint4 v0 = *(const uint4*)&Vt[t * 16 + lm][l4 * 8];
      uint4 v1 = *(const uint4*)&Vt[t * 16 + lm][32 + l4 * 8];
      acc[t] = mfma16(pa0, v0, acc[t]);
      acc[t] = mfma16(pa1, v1, acc[t]);
    }
    __syncthreads();
  }

  // ---- epilogue: ctx[b, s, h*64 + d] ----
  const int b = bh >> 4, h = bh & 15;
  #pragma unroll
  for (int t = 0; t < 4; ++t)
    #pragma unroll
    for (int r = 0; r < 4; ++r){
      int srow = qbase + l4 * 4 + r;
      float val = acc[t][r] / lsum[r];
      ctx[((size_t)b * S_LEN + srow) * HIDDEN + h * HDIM + t * 16 + lm] = f2bf(val);
    }
}

// ---------------- launch ----------------
extern "C" void kernel_launch(void* const* d_in, const int* in_sizes, int n_in,
                              void* d_out, int out_size, void* d_ws, size_t ws_size,
                              hipStream_t stream)
{
  const float* x     = (const float*)d_in[0];
  // d_in[1] = causal mask (structure known; ignored)
  const float* w_qkv = (const float*)d_in[2];
  const float* b_qkv = (const float*)d_in[3];
  const float* w_out = (const float*)d_in[4];
  const float* b_out = (const float*)d_in[5];

  char* ws = (char*)d_ws;
  u16* xbf   = (u16*)(ws);                 // 16,777,216 B (reused as ctx later)
  u16* wqkvT = (u16*)(ws + 16777216);      //  6,291,456 B
  u16* woutT = (u16*)(ws + 23068672);      //  2,097,152 B
  u16* qb    = (u16*)(ws + 25165824);      // 16,777,216 B
  u16* kb    = (u16*)(ws + 41943040);      // 16,777,216 B
  u16* vb    = (u16*)(ws + 58720256);      // 16,777,216 B  (total 75,497,472 B)

  k_cvt<<<2048, 256, 0, stream>>>(x, xbf, (BATCH * S_LEN * HIDDEN) / 4);
  k_transpose<<<dim3(96, 32), 256, 0, stream>>>(w_qkv, wqkvT, HIDDEN, 3 * HIDDEN);
  k_transpose<<<dim3(32, 32), 256, 0, stream>>>(w_out, woutT, HIDDEN, HIDDEN);
  k_gemm<0><<<dim3(24, 64), 256, 0, stream>>>(xbf, wqkvT, b_qkv,
                                              qb, kb, vb, nullptr,
                                              BATCH * S_LEN, 3 * HIDDEN, HIDDEN);
  k_attn<<<2048, 256, 0, stream>>>(qb, kb, vb, xbf);
  k_gemm<1><<<dim3(8, 64), 256, 0, stream>>>(xbf, woutT, b_out,
                                             nullptr, nullptr, nullptr,
                                             (float*)d_out, BATCH * S_LEN, HIDDEN, HIDDEN);
}

// Round 2
// 288.433 us; speedup vs baseline: 1.3054x; 1.3054x over previous
//
#include <hip/hip_runtime.h>
#include <stdint.h>

#define S_LEN 2048
#define NHEAD 16
#define HDIM  64
#define HIDDEN 1024
#define BATCH 4

typedef float f32x4 __attribute__((ext_vector_type(4)));
typedef __bf16 bf16x8 __attribute__((ext_vector_type(8)));
typedef unsigned short u16;

union U4B8 { uint4 u; bf16x8 b; };

__device__ __forceinline__ bf16x8 as_b8(uint4 u){ U4B8 x; x.u = u; return x.b; }

__device__ __forceinline__ f32x4 mfma16(uint4 a, uint4 b, f32x4 c){
  return __builtin_amdgcn_mfma_f32_16x16x32_bf16(as_b8(a), as_b8(b), c, 0, 0, 0);
}

__device__ __forceinline__ u16 f2bf(float f){
  unsigned u = __float_as_uint(f);
  u += 0x7FFFu + ((u >> 16) & 1u);
  return (u16)(u >> 16);
}

__device__ __forceinline__ void gload16(const void* g, void* l){
  __builtin_amdgcn_global_load_lds(
      (const __attribute__((address_space(1))) unsigned int*)g,
      (__attribute__((address_space(3))) unsigned int*)l, 16, 0, 0);
}

// ---------------- convert x: f32 -> bf16, 4 elems/thread/iter ----------------
__global__ __launch_bounds__(256) void k_cvt(const float* __restrict__ in,
                                             u16* __restrict__ out, int n4){
  int i = blockIdx.x * 256 + threadIdx.x;
  int stride = gridDim.x * 256;
  for (; i < n4; i += stride){
    float4 v = ((const float4*)in)[i];
    unsigned lo = (unsigned)f2bf(v.x) | ((unsigned)f2bf(v.y) << 16);
    unsigned hi = (unsigned)f2bf(v.z) | ((unsigned)f2bf(v.w) << 16);
    ((uint2*)out)[i] = make_uint2(lo, hi);
  }
}

// ---------------- transpose+convert: f32 [K][N] -> bf16 [N][K] ----------------
__global__ __launch_bounds__(256) void k_transpose(const float* __restrict__ in,
                                                   u16* __restrict__ out,
                                                   int K, int N){
  __shared__ float t[32][33];
  int tx = threadIdx.x & 31, ty = threadIdx.x >> 5;
  int n0 = blockIdx.x * 32, k0 = blockIdx.y * 32;
  #pragma unroll
  for (int i = 0; i < 4; ++i)
    t[ty + i*8][tx] = in[(size_t)(k0 + ty + i*8) * N + n0 + tx];
  __syncthreads();
  #pragma unroll
  for (int i = 0; i < 4; ++i)
    out[(size_t)(n0 + ty + i*8) * K + k0 + tx] = f2bf(t[tx][ty + i*8]);
}

// ---------------- GEMM: C[M,N] = A[M,K](bf16) @ Bt[N,K](bf16)^T + bias -------
// MODE 0: scatter into q/k [B*H][S][D] bf16 and V TRANSPOSED [B*H][D][S].
// MODE 1: f32 out [M,N].
template<int MODE>
__global__ __launch_bounds__(256) void k_gemm(
    const u16* __restrict__ A, const u16* __restrict__ Bt,
    const float* __restrict__ bias,
    u16* __restrict__ oq, u16* __restrict__ ok, u16* __restrict__ ov,
    float* __restrict__ of, int M, int N, int K)
{
  __shared__ u16 As[128 * 32];
  __shared__ u16 Bs[128 * 32];
  const int tid  = threadIdx.x;
  const int wave = tid >> 6, lane = tid & 63;
  const int l4 = lane >> 4, lm = lane & 15;
  const int wr = wave >> 1, wc = wave & 1;
  const int row0 = blockIdx.y * 128;
  const int col0 = blockIdx.x * 128;

  const f32x4 fzero = {0.f, 0.f, 0.f, 0.f};
  f32x4 acc[4][4];
  #pragma unroll
  for (int m = 0; m < 4; ++m)
    #pragma unroll
    for (int n = 0; n < 4; ++n) acc[m][n] = fzero;

  for (int k0 = 0; k0 < K; k0 += 32){
    #pragma unroll
    for (int p = 0; p < 2; ++p){
      int chunk = wave * 128 + p * 64 + lane;
      int r = chunk >> 2, cseg = chunk & 3;
      const u16* ga = A  + (size_t)(row0 + r) * K + k0 + cseg * 8;
      gload16(ga, &As[(wave * 128 + p * 64) * 8]);
      const u16* gb = Bt + (size_t)(col0 + r) * K + k0 + cseg * 8;
      gload16(gb, &Bs[(wave * 128 + p * 64) * 8]);
    }
    __syncthreads();
    uint4 af[4], bf[4];
    #pragma unroll
    for (int m = 0; m < 4; ++m)
      af[m] = *(const uint4*)&As[(wr * 64 + m * 16 + lm) * 32 + l4 * 8];
    #pragma unroll
    for (int n = 0; n < 4; ++n)
      bf[n] = *(const uint4*)&Bs[(wc * 64 + n * 16 + lm) * 32 + l4 * 8];
    #pragma unroll
    for (int m = 0; m < 4; ++m)
      #pragma unroll
      for (int n = 0; n < 4; ++n)
        acc[m][n] = mfma16(af[m], bf[n], acc[m][n]);
    __syncthreads();
  }

  #pragma unroll
  for (int m = 0; m < 4; ++m){
    #pragma unroll
    for (int n = 0; n < 4; ++n){
      int c = col0 + wc * 64 + n * 16 + lm;
      float bv = bias[c];
      #pragma unroll
      for (int r = 0; r < 4; ++r){
        int row = row0 + wr * 64 + m * 16 + l4 * 4 + r;
        float val = acc[m][n][r] + bv;
        if (MODE == 0){
          int h = c / 192, e = c % 192;
          int which = e >> 6, d = e & 63;
          int b = row >> 11, s = row & 2047;
          int bh = b * 16 + h;
          if (which == 2){
            // V stored transposed: [bh][d][s]
            ov[((size_t)bh * HDIM + d) * S_LEN + s] = f2bf(val);
          } else {
            size_t idx = ((size_t)bh * S_LEN + s) * HDIM + d;
            u16* dst = (which == 0) ? oq : ok;
            dst[idx] = f2bf(val);
          }
        } else {
          of[(size_t)row * N + c] = val;
        }
      }
    }
  }
}

// ---------------- causal flash attention, barrier-free ----------------
// grid: 1024 blocks. bh = bid&63, btile = 15 - (bid>>6) (heavy first).
// Each wave independently owns 32 q-rows (2 x 16-row fragments).
// K read [bh][s][d] row-major; V read PRE-TRANSPOSED [bh][d][s].
// Only LDS use: per-wave P round-trip (wave_barrier only, no __syncthreads).
__global__ __launch_bounds__(256) void k_attn(
    const u16* __restrict__ q, const u16* __restrict__ kk,
    const u16* __restrict__ vt, u16* __restrict__ ctx)
{
  __shared__ u16 Ps[4][2][16][68];

  const int bid = blockIdx.x;
  const int bh = bid & 63;
  const int btile = 15 - (bid >> 6);
  const int wave = threadIdx.x >> 6, lane = threadIdx.x & 63;
  const int l4 = lane >> 4, lm = lane & 15;
  const int q0 = btile * 128 + wave * 32;
  const size_t base = (size_t)bh * (S_LEN * HDIM);
  const u16* kB = kk + base;
  const u16* vB = vt + base;   // [d][s]

  uint4 qf[2][2];
  #pragma unroll
  for (int f = 0; f < 2; ++f){
    const u16* qr = q + base + (size_t)(q0 + f * 16 + lm) * HDIM + l4 * 8;
    qf[f][0] = *(const uint4*)qr;
    qf[f][1] = *(const uint4*)(qr + 32);
  }

  const f32x4 fz = {0.f, 0.f, 0.f, 0.f};
  float mr[2][4], ls[2][4];
  f32x4 acc[2][4];
  #pragma unroll
  for (int f = 0; f < 2; ++f)
    #pragma unroll
    for (int r = 0; r < 4; ++r){ mr[f][r] = -1e30f; ls[f][r] = 0.f; }
  #pragma unroll
  for (int f = 0; f < 2; ++f)
    #pragma unroll
    for (int t = 0; t < 4; ++t) acc[f][t] = fz;

  const int nkt = (q0 + 31) / 64 + 1;
  for (int kt = 0; kt < nkt; ++kt){
    const int kbase = kt * 64;

    // ---- S = Q K^T : K fragments straight from global (L2) ----
    f32x4 sv[2][4];
    #pragma unroll
    for (int g = 0; g < 4; ++g){
      const u16* kr = kB + (size_t)(kbase + g * 16 + lm) * HDIM + l4 * 8;
      uint4 b0 = *(const uint4*)kr;
      uint4 b1 = *(const uint4*)(kr + 32);
      sv[0][g] = mfma16(qf[0][0], b0, fz);
      sv[0][g] = mfma16(qf[0][1], b1, sv[0][g]);
      sv[1][g] = mfma16(qf[1][0], b0, fz);
      sv[1][g] = mfma16(qf[1][1], b1, sv[1][g]);
    }

    // ---- softmax (online), per q-fragment ----
    #pragma unroll
    for (int f = 0; f < 2; ++f){
      float sr[4][4];
      #pragma unroll
      for (int g = 0; g < 4; ++g)
        #pragma unroll
        for (int r = 0; r < 4; ++r) sr[g][r] = sv[f][g][r] * 0.125f;

      if (kt == nkt - 1){
        #pragma unroll
        for (int g = 0; g < 4; ++g)
          #pragma unroll
          for (int r = 0; r < 4; ++r){
            int kg = kbase + g * 16 + lm;
            int qg = q0 + f * 16 + l4 * 4 + r;
            if (kg > qg) sr[g][r] = -1e30f;
          }
      }

      float pm[4];
      #pragma unroll
      for (int r = 0; r < 4; ++r)
        pm[r] = fmaxf(fmaxf(sr[0][r], sr[1][r]), fmaxf(sr[2][r], sr[3][r]));
      #pragma unroll
      for (int off = 1; off < 16; off <<= 1)
        #pragma unroll
        for (int r = 0; r < 4; ++r)
          pm[r] = fmaxf(pm[r], __shfl_xor(pm[r], off));

      float psum[4];
      #pragma unroll
      for (int r = 0; r < 4; ++r){
        float mn = fmaxf(mr[f][r], pm[r]);
        float corr = __expf(mr[f][r] - mn);
        mr[f][r] = mn;
        ls[f][r] *= corr;
        #pragma unroll
        for (int t = 0; t < 4; ++t) acc[f][t][r] *= corr;
        float s_ = 0.f;
        #pragma unroll
        for (int g = 0; g < 4; ++g){
          float e = __expf(sr[g][r] - mn);
          sr[g][r] = e;
          s_ += e;
        }
        psum[r] = s_;
      }
      #pragma unroll
      for (int off = 1; off < 16; off <<= 1)
        #pragma unroll
        for (int r = 0; r < 4; ++r)
          psum[r] += __shfl_xor(psum[r], off);
      #pragma unroll
      for (int r = 0; r < 4; ++r) ls[f][r] += psum[r];

      // P -> bf16 -> per-wave LDS
      #pragma unroll
      for (int g = 0; g < 4; ++g)
        #pragma unroll
        for (int r = 0; r < 4; ++r)
          Ps[wave][f][l4 * 4 + r][g * 16 + lm] = f2bf(sr[g][r]);
    }

    __builtin_amdgcn_wave_barrier();
    uint4 pa[2][2];
    #pragma unroll
    for (int f = 0; f < 2; ++f){
      pa[f][0] = *(const uint4*)&Ps[wave][f][lm][l4 * 8];
      pa[f][1] = *(const uint4*)&Ps[wave][f][lm][32 + l4 * 8];
    }

    // ---- O += P @ V : V^T fragments straight from global (L2) ----
    #pragma unroll
    for (int t = 0; t < 4; ++t){
      const u16* vr = vB + (size_t)(t * 16 + lm) * S_LEN + kbase + l4 * 8;
      uint4 v0 = *(const uint4*)vr;
      uint4 v1 = *(const uint4*)(vr + 32);
      acc[0][t] = mfma16(pa[0][0], v0, acc[0][t]);
      acc[0][t] = mfma16(pa[0][1], v1, acc[0][t]);
      acc[1][t] = mfma16(pa[1][0], v0, acc[1][t]);
      acc[1][t] = mfma16(pa[1][1], v1, acc[1][t]);
    }
  }

  // ---- epilogue ----
  const int b = bh >> 4, h = bh & 15;
  float inv[2][4];
  #pragma unroll
  for (int f = 0; f < 2; ++f)
    #pragma unroll
    for (int r = 0; r < 4; ++r) inv[f][r] = 1.0f / ls[f][r];
  #pragma unroll
  for (int f = 0; f < 2; ++f)
    #pragma unroll
    for (int t = 0; t < 4; ++t)
      #pragma unroll
      for (int r = 0; r < 4; ++r){
        int srow = q0 + f * 16 + l4 * 4 + r;
        float val = acc[f][t][r] * inv[f][r];
        ctx[((size_t)b * S_LEN + srow) * HIDDEN + h * HDIM + t * 16 + lm] = f2bf(val);
      }
}

// ---------------- launch ----------------
extern "C" void kernel_launch(void* const* d_in, const int* in_sizes, int n_in,
                              void* d_out, int out_size, void* d_ws, size_t ws_size,
                              hipStream_t stream)
{
  const float* x     = (const float*)d_in[0];
  // d_in[1] = causal mask (structure known; ignored)
  const float* w_qkv = (const float*)d_in[2];
  const float* b_qkv = (const float*)d_in[3];
  const float* w_out = (const float*)d_in[4];
  const float* b_out = (const float*)d_in[5];

  char* ws = (char*)d_ws;
  u16* xbf   = (u16*)(ws);                 // 16 MB (reused as ctx)
  u16* wqkvT = (u16*)(ws + 16777216);      //  6 MB
  u16* woutT = (u16*)(ws + 23068672);      //  2 MB
  u16* qb    = (u16*)(ws + 25165824);      // 16 MB
  u16* kb    = (u16*)(ws + 41943040);      // 16 MB
  u16* vb    = (u16*)(ws + 58720256);      // 16 MB   V^T: [bh][d][s]

  k_cvt<<<2048, 256, 0, stream>>>(x, xbf, (BATCH * S_LEN * HIDDEN) / 4);
  k_transpose<<<dim3(96, 32), 256, 0, stream>>>(w_qkv, wqkvT, HIDDEN, 3 * HIDDEN);
  k_transpose<<<dim3(32, 32), 256, 0, stream>>>(w_out, woutT, HIDDEN, HIDDEN);
  k_gemm<0><<<dim3(24, 64), 256, 0, stream>>>(xbf, wqkvT, b_qkv,
                                              qb, kb, vb, nullptr,
                                              BATCH * S_LEN, 3 * HIDDEN, HIDDEN);
  k_attn<<<1024, 256, 0, stream>>>(qb, kb, vb, xbf);
  k_gemm<1><<<dim3(8, 64), 256, 0, stream>>>(xbf, woutT, b_out,
                                             nullptr, nullptr, nullptr,
                                             (float*)d_out, BATCH * S_LEN, HIDDEN, HIDDEN);
}